// Round 7
// baseline (813.564 us; speedup 1.0000x reference)
//
#include <hip/hip_runtime.h>
#include <stdint.h>

typedef __bf16 bf16;
typedef __bf16 bf16x4v __attribute__((ext_vector_type(4)));
typedef __bf16 bf16x8 __attribute__((ext_vector_type(8)));
typedef float floatx4 __attribute__((ext_vector_type(4)));
typedef float float4v __attribute__((ext_vector_type(4)));

#define SCALE 0.17677669529663689f

// load input element i as float, honoring runtime dtype flag (1 = fp32, 0 = bf16)
__device__ __forceinline__ float ldin(const void* p, long i, int f32) {
  return f32 ? ((const float*)p)[i] : (float)(((const bf16*)p)[i]);
}

// async global->LDS DMA, 16B per lane. lds ptr must be wave-uniform;
// HW writes lds_base + lane*16.
__device__ __forceinline__ void async16(const bf16* g, bf16* l) {
  __builtin_amdgcn_global_load_lds(
      (const __attribute__((address_space(1))) void*)g,
      (__attribute__((address_space(3))) void*)l, 16, 0, 0);
}

// ---------------- dtype detector ----------------
__global__ void detect_k(const unsigned short* __restrict__ x, int* flag) {
  __shared__ int cnt;
  if (threadIdx.x == 0) cnt = 0;
  __syncthreads();
  int local = 0;
  for (int i = threadIdx.x; i < 4096; i += 256) {
    unsigned short w = x[i];
    int e = (w >> 7) & 0xFF;
    if (w != 0 && (e >= 0x9F || e <= 0x5F)) local++;
  }
  atomicAdd(&cnt, local);
  __syncthreads();
  if (threadIdx.x == 0) *flag = (cnt >= 64) ? 1 : 0;
}

// ---------------- weight convert+transpose: W[K][N] -> Wt[N][K] (bf16) ----------------
__global__ void conv_w_k(const void* __restrict__ W, bf16* __restrict__ Wt,
                         int K, int N, const int* __restrict__ flag) {
  int f32 = *flag;
  int idx = blockIdx.x * 256 + threadIdx.x;
  if (idx < K * N) {
    int k = idx / N, n = idx % N;
    Wt[n * K + k] = (bf16)ldin(W, idx, f32);
  }
}

// three 256x256 weight converts in one launch
__global__ void conv3_k(const void* __restrict__ W0, const void* __restrict__ W1,
                        const void* __restrict__ W2, bf16* __restrict__ T0,
                        bf16* __restrict__ T1, bf16* __restrict__ T2,
                        const int* __restrict__ flag) {
  int f32 = *flag;
  int which = blockIdx.x >> 8;
  int idx = (blockIdx.x & 255) * 256 + threadIdx.x;
  const void* W = which == 0 ? W0 : which == 1 ? W1 : W2;
  bf16* T = which == 0 ? T0 : which == 1 ? T1 : T2;
  int k = idx >> 8, n = idx & 255;
  T[n * 256 + k] = (bf16)ldin(W, idx, f32);
}

// ---------------- rel-bias precompute into MFMA C-order table ----------------
// bias_s[head][quad][l16][mi][ni][r]  (fp32, 32768 entries = 128 KB)
__global__ void bias_k(const void* __restrict__ rel, float* __restrict__ bias_s,
                       const int* __restrict__ flag) {
  int f = *flag;
  int idx = blockIdx.x * 256 + threadIdx.x;  // 0..32767
  int r = idx & 3, ni = (idx >> 2) & 3, mi = (idx >> 4) & 3;
  int l16 = (idx >> 6) & 15, quad = (idx >> 10) & 3, head = idx >> 12;
  int i = mi * 16 + quad * 4 + r, j = ni * 16 + l16;
  int dy = (i >> 3) - (j >> 3) + 7, dx = (i & 7) - (j & 7) + 7;
  bias_s[idx] = ldin(rel, (dy * 15 + dx) * 8 + head, f);
}

// ---------------- LayerNorm: rows of 256, 1 wave per row ----------------
__global__ __launch_bounds__(256) void ln_k(const void* __restrict__ x,
                                            const void* __restrict__ g,
                                            const void* __restrict__ b,
                                            bf16* __restrict__ y,
                                            const int* __restrict__ flag,
                                            int x_input) {
  int f = *flag;
  int f32x = x_input ? f : 0;
  int wave = threadIdx.x >> 6, lane = threadIdx.x & 63;
  long row = (long)blockIdx.x * 4 + wave;
  float v[4];
  if (f32x) {
    float4v u = ((const float4v*)x)[row * 64 + lane];
    for (int i = 0; i < 4; i++) v[i] = u[i];
  } else {
    bf16x4v u = ((const bf16x4v*)x)[row * 64 + lane];
    for (int i = 0; i < 4; i++) v[i] = (float)u[i];
  }
  float s = v[0] + v[1] + v[2] + v[3];
  for (int off = 32; off > 0; off >>= 1) s += __shfl_xor(s, off, 64);
  float mean = s * (1.f / 256.f);
  float q = 0.f;
  for (int i = 0; i < 4; i++) { float d = v[i] - mean; q += d * d; }
  for (int off = 32; off > 0; off >>= 1) q += __shfl_xor(q, off, 64);
  float rstd = rsqrtf(q * (1.f / 256.f) + 1e-5f);
  bf16x4v o;
  for (int i = 0; i < 4; i++) {
    float gv = ldin(g, lane * 4 + i, f);
    float bv = ldin(b, lane * 4 + i, f);
    o[i] = (bf16)((v[i] - mean) * rstd * gv + bv);
  }
  ((bf16x4v*)y)[row * 64 + lane] = o;
}

// ------------- GEMM C[M][N] = A[M][K] @ Bt[N][K]^T + bias (+epilogue) -------------
// grid = dim3(N/128, M/128), bijective XCD chunk swizzle.
// A: global_load_lds (w=16) double-buffered, source-side XOR swizzle + same XOR
//    on fragment ds_read -> 0 bank conflicts (verified R2).
// B (weights, L2-resident): loaded DIRECT global->reg, software-pipelined one
//    tile ahead with statically-named parity register sets (no LDS staging,
//    no barrier coupling) — halves LDS-pipe traffic, the R6 limiter.
// K-loop asm-free: one __syncthreads() per tile (R5 form).
// Requires K % 64 == 0 (all call sites use K=256).
// Epilogue stages C through LDS (CsF aliases the A buffers) so stores are
// wide & line-coalesced; EPI==2 residual added in store phase, vectorized.
template <int EPI>
__global__ __launch_bounds__(256) void gemm_bt_k(
    const bf16* __restrict__ A, const bf16* __restrict__ Bt,
    const void* __restrict__ bias, const void* __restrict__ res,
    void* __restrict__ C, int M, int N, int K, const int* __restrict__ flag,
    int res_input, int out_input) {
  __shared__ __align__(16) char smem[16896];  // 2 x 8KB A bufs; CsF alias
  bf16* Sb = (bf16*)smem;
  float* CsF = (float*)smem;  // 32x132 fp32, live only after K-loop

  const int tid = threadIdx.x;
  const int ntiles = gridDim.x;  // N/128
  int bid = blockIdx.y * ntiles + blockIdx.x;
  const int nwg = ntiles * gridDim.y;
  if (!(nwg & 7)) bid = (bid & 7) * (nwg >> 3) + (bid >> 3);  // XCD chunking
  const long m0 = (long)(bid / ntiles) * 128;
  const int n0 = (bid % ntiles) * 128;
  const int wave = tid >> 6, lane = tid & 63;
  const int wm = wave & 1, wn = wave >> 1;
  const int quad = lane >> 4, l16 = lane & 15;

  floatx4 acc[4][4];
  for (int i = 0; i < 4; i++)
    for (int j = 0; j < 4; j++) acc[i][j] = (floatx4){0.f, 0.f, 0.f, 0.f};

  const int ldr = tid >> 2;
  // source-side swizzle: lds slot (row, c) receives global chunk c ^ ((row>>1)&3)
  const int ldc = (((tid & 3) ^ ((tid >> 3) & 3)) << 3);

  const bf16* gA0 = A + (m0 + ldr) * K + ldc;
  const bf16* gA1 = A + (m0 + 64 + ldr) * K + ldc;
  // direct B fragment base: row n0 + wn*64 + ni*16 + l16, col chunk quad*8
  const bf16* gB = Bt + (long)(n0 + wn * 64 + l16) * K + quad * 8;
  const long bstride = (long)16 * K;  // ni step

  const int rswz = (l16 >> 1) & 3;  // read-side XOR (row = ..16.. + l16)
  const int NT = K >> 5;            // K-tiles (8 for K=256); must be even >= 2

  // stage A tile tt into buffer b (2 DMAs per wave, wave-uniform LDS bases)
#define STAGE_A(b, tt)                                 \
  do {                                                 \
    bf16* _base = Sb + (b) * 4096 + wave * 512;        \
    int _kt = (tt) << 5;                               \
    async16(gA0 + _kt, _base);                         \
    async16(gA1 + _kt, _base + 2048);                  \
  } while (0)

#define BLOAD(dst, tt)                                                 \
  do {                                                                 \
    int _kt = (tt) << 5;                                               \
    for (int _ni = 0; _ni < 4; _ni++)                                  \
      dst[_ni] = *(const bf16x8*)(gB + _ni * bstride + _kt);           \
  } while (0)

#define COMPUTE(bufidx, bfrag)                                          \
  do {                                                                  \
    const bf16* As_t = Sb + (bufidx) * 4096;                            \
    bf16x8 af[4];                                                       \
    for (int mi = 0; mi < 4; mi++)                                      \
      af[mi] = *(const bf16x8*)&As_t[(wm * 64 + mi * 16 + l16) * 32 +   \
                                     ((quad ^ rswz) << 3)];             \
    for (int mi = 0; mi < 4; mi++)                                      \
      for (int ni = 0; ni < 4; ni++)                                    \
        acc[mi][ni] = __builtin_amdgcn_mfma_f32_16x16x32_bf16(          \
            af[mi], bfrag[ni], acc[mi][ni], 0, 0, 0);                   \
  } while (0)

  bf16x8 bf0[4], bf1[4];
  STAGE_A(0, 0);
  BLOAD(bf0, 0);
  __syncthreads();  // tile 0 A landed (drains B0 too)

  for (int t = 0; t < NT; t += 2) {
    // ---- even tile t (buf 0, frags bf0) ----
    if (t + 1 < NT) { STAGE_A(1, t + 1); BLOAD(bf1, t + 1); }
    COMPUTE(0, bf0);
    __syncthreads();  // tile t+1 A landed; buf0 reads done
    // ---- odd tile t+1 (buf 1, frags bf1) ----
    if (t + 2 < NT) { STAGE_A(0, t + 2); BLOAD(bf0, t + 2); }
    COMPUTE(1, bf1);
    __syncthreads();  // tile t+2 A landed; buf1 reads done
  }
#undef STAGE_A
#undef BLOAD
#undef COMPUTE

  const int f = *flag;
  const int rf32 = res_input ? f : 0;
  const int of32 = out_input ? f : 0;
  for (int mi = 0; mi < 4; mi++) {
    __syncthreads();  // CsF free (K-loop reads / prev store phase done)
    // ---- reg phase: bias / GELU, stage into LDS ----
    for (int ni = 0; ni < 4; ni++) {
      int col = n0 + wn * 64 + ni * 16 + l16;
      float bv = ldin(bias, col, f);
      for (int r = 0; r < 4; r++) {
        float v = acc[mi][ni][r] + bv;
        if (EPI == 1) v = v * 0.5f * (1.f + erff(v * 0.70710678118654752f));
        CsF[(wm * 16 + quad * 4 + r) * 132 + wn * 64 + ni * 16 + l16] = v;
      }
    }
    __syncthreads();
    // ---- store phase: each thread writes 16 contiguous cols of one row ----
    const int s = tid >> 3;   // 0..31 staged rows
    const int seg = tid & 7;  // 8 x 16-col segments
    const long grow = m0 + (s >> 4) * 64 + mi * 16 + (s & 15);
    const int gcol = n0 + seg * 16;
    const float4v* src = (const float4v*)&CsF[s * 132 + seg * 16];
    float4v v0 = src[0], v1 = src[1], v2 = src[2], v3 = src[3];
    if (EPI == 2) {  // residual add, vectorized & coalesced
      if (rf32) {
        const float4v* rp = (const float4v*)((const float*)res + grow * N + gcol);
        v0 += rp[0]; v1 += rp[1]; v2 += rp[2]; v3 += rp[3];
      } else {
        const bf16x8* rp = (const bf16x8*)((const bf16*)res + grow * N + gcol);
        bf16x8 r0 = rp[0], r1 = rp[1];
        for (int j = 0; j < 4; j++) {
          v0[j] += (float)r0[j];     v1[j] += (float)r0[4 + j];
          v2[j] += (float)r1[j];     v3[j] += (float)r1[4 + j];
        }
      }
    }
    if (of32) {
      float4v* dst = (float4v*)((float*)C + grow * N + gcol);
      dst[0] = v0; dst[1] = v1; dst[2] = v2; dst[3] = v3;
    } else {
      bf16x8 o0, o1;
      for (int j = 0; j < 4; j++) {
        o0[j] = (bf16)v0[j]; o0[4 + j] = (bf16)v1[j];
        o1[j] = (bf16)v2[j]; o1[4 + j] = (bf16)v3[j];
      }
      bf16x8* dst = (bf16x8*)((bf16*)C + grow * N + gcol);
      dst[0] = o0; dst[1] = o1;
    }
  }
}

// ---------------- MFMA windowed attention ----------------
// 1 wave = 1 (window, head); block = 4 heads of same window.
// qkv: [131072][768] bf16; o: [131072][256] bf16; bias_s: MFMA C-order fp32.
__global__ __launch_bounds__(256) void attn_k(const bf16* __restrict__ qkv,
                                              const float* __restrict__ bias_s,
                                              bf16* __restrict__ o) {
  __shared__ bf16 Pb[4][64 * 64];
  __shared__ bf16 Vb[4][32 * 64];
  const int tid = threadIdx.x;
  const int wave = tid >> 6, lane = tid & 63;
  const int quad = lane >> 4, l16 = lane & 15;
  const int gid = blockIdx.x * 4 + wave;
  const int head = gid & 7, win = gid >> 3;
  const int wx = win & 15, wy = (win >> 4) & 15, bb = win >> 8;

  bf16* P = Pb[wave];
  bf16* Vt = Vb[wave];

  // --- load Q,K fragments direct from global; V natural -> LDS transposed ---
  bf16x8 qf[4], kf[4];
  for (int mi = 0; mi < 4; mi++) {
    int t = mi * 16 + l16;
    int rr = (wy * 8 + (t >> 3) + 4) & 127;
    int cc = (wx * 8 + (t & 7) + 4) & 127;
    long base = ((long)(bb * 16384 + rr * 128 + cc)) * 768 + head * 32 + quad * 8;
    qf[mi] = *(const bf16x8*)(qkv + base);
    kf[mi] = *(const bf16x8*)(qkv + base + 256);
    bf16x8 vv = *(const bf16x8*)(qkv + base + 512);
    // Vt[d][t] stored at d*64 + (t ^ ((d>>3)<<4)); here d = quad*8+jj, d>>3 = quad
    int tcol = t ^ (quad << 4);
    for (int jj = 0; jj < 8; jj++) Vt[(quad * 8 + jj) * 64 + tcol] = vv[jj];
  }
  __syncthreads();

  // --- S = Q K^T (16 MFMAs, K=32 single step) ---
  floatx4 acc[4][4];
  for (int mi = 0; mi < 4; mi++)
    for (int ni = 0; ni < 4; ni++) {
      floatx4 z = (floatx4){0.f, 0.f, 0.f, 0.f};
      acc[mi][ni] = __builtin_amdgcn_mfma_f32_16x16x32_bf16(qf[mi], kf[ni], z, 0, 0, 0);
    }

  // --- scale + bias + row softmax (rows live in one quad -> shfl over l16) ---
  const float4v* bp =
      (const float4v*)(bias_s + (((head * 4 + quad) * 16 + l16) << 6));
  for (int mi = 0; mi < 4; mi++) {
    float mx[4] = {-1e30f, -1e30f, -1e30f, -1e30f};
    for (int ni = 0; ni < 4; ni++) {
      float4v bv = bp[mi * 4 + ni];
      for (int r = 0; r < 4; r++) {
        acc[mi][ni][r] = acc[mi][ni][r] * SCALE + bv[r];
        mx[r] = fmaxf(mx[r], acc[mi][ni][r]);
      }
    }
    for (int r = 0; r < 4; r++) {
      float m = mx[r];
      for (int off = 1; off < 16; off <<= 1) m = fmaxf(m, __shfl_xor(m, off, 64));
      mx[r] = m;
    }
    float sm[4] = {0.f, 0.f, 0.f, 0.f};
    for (int ni = 0; ni < 4; ni++)
      for (int r = 0; r < 4; r++) {
        float e = __expf(acc[mi][ni][r] - mx[r]);
        acc[mi][ni][r] = e;
        sm[r] += e;
      }
    for (int r = 0; r < 4; r++) {
      float s = sm[r];
      for (int off = 1; off < 16; off <<= 1) s += __shfl_xor(s, off, 64);
      sm[r] = 1.f / s;
    }
    // P[i][j] stored at i*64 + (j ^ ((i&7)<<3))
    for (int ni = 0; ni < 4; ni++)
      for (int r = 0; r < 4; r++) {
        int i = mi * 16 + quad * 4 + r;
        int j = ni * 16 + l16;
        P[i * 64 + (j ^ ((i & 7) << 3))] = (bf16)(acc[mi][ni][r] * sm[r]);
      }
  }
  __syncthreads();

  // --- O = P V (16 MFMAs over 2 K-steps) ---
  floatx4 oacc[4][2];
  for (int mi = 0; mi < 4; mi++)
    for (int nt = 0; nt < 2; nt++) oacc[mi][nt] = (floatx4){0.f, 0.f, 0.f, 0.f};
  for (int ks = 0; ks < 2; ks++) {
    bf16x8 vfr[2];
    for (int nt = 0; nt < 2; nt++) {
      int d = nt * 16 + l16;
      vfr[nt] =
          *(const bf16x8*)&Vt[d * 64 + ((ks * 32 + quad * 8) ^ ((d >> 3) << 4))];
    }
    for (int mi = 0; mi < 4; mi++) {
      int i = mi * 16 + l16;
      bf16x8 pf =
          *(const bf16x8*)&P[i * 64 + ((ks * 32 + quad * 8) ^ ((i & 7) << 3))];
      for (int nt = 0; nt < 2; nt++)
        oacc[mi][nt] = __builtin_amdgcn_mfma_f32_16x16x32_bf16(pf, vfr[nt],
                                                               oacc[mi][nt], 0, 0, 0);
    }
  }

  // --- stage O into Vt (wave-private, dead after PV; chunk-rotated to spread
  //     banks) then write 64B per token with 4x16B stores ---
  for (int mi = 0; mi < 4; mi++)
    for (int r = 0; r < 4; r++) {
      int t = mi * 16 + quad * 4 + r;
      int rot = (t >> 1) & 3;
      int c0 = l16, c1 = 16 + l16;
      Vt[t * 32 + ((((c0 >> 3) + rot) & 3) << 3) + (c0 & 7)] = (bf16)oacc[mi][0][r];
      Vt[t * 32 + ((((c1 >> 3) + rot) & 3) << 3) + (c1 & 7)] = (bf16)oacc[mi][1][r];
    }
  {
    int t = lane;
    int rot = (t >> 1) & 3;
    int rr = (wy * 8 + (t >> 3) + 4) & 127;
    int cc = (wx * 8 + (t & 7) + 4) & 127;
    long base = ((long)(bb * 16384 + rr * 128 + cc)) * 256 + head * 32;
    bf16x8* dst = (bf16x8*)(o + base);
    for (int k = 0; k < 4; k++)
      dst[k] = *(const bf16x8*)&Vt[t * 32 + (((k + rot) & 3) << 3)];
  }
}

extern "C" void kernel_launch(void* const* d_in, const int* in_sizes, int n_in,
                              void* d_out, int out_size, void* d_ws,
                              size_t ws_size, hipStream_t stream) {
  const void* x = d_in[0];
  const void* n1g = d_in[1];
  const void* n1b = d_in[2];
  const void* qkv_w = d_in[3];
  const void* qkv_b = d_in[4];
  const void* rel_bias = d_in[5];
  const void* proj_w = d_in[6];
  const void* proj_b = d_in[7];
  const void* n2g = d_in[8];
  const void* n2b = d_in[9];
  const void* fc1_w = d_in[10];
  const void* fc1_b = d_in[11];
  const void* fc2_w = d_in[12];
  const void* fc2_b = d_in[13];

  char* ws = (char*)d_ws;
  int* flag = (int*)ws;
  float* bias_s = (float*)(ws + 4096);        // 128 KB
  bf16* qkvWt = (bf16*)(ws + 262144);         // 768*256 bf16
  bf16* projWt = qkvWt + 768 * 256;
  bf16* fc1Wt = projWt + 256 * 256;
  bf16* fc2Wt = fc1Wt + 256 * 256;
  bf16* reg1 = (bf16*)(ws + (1 << 20));                  // 64 MiB region
  bf16* reg2 = (bf16*)(ws + (1 << 20) + 67108864);       // 192 MiB region

  const int M = 131072;  // 8 * 16384 tokens

  detect_k<<<1, 256, 0, stream>>>((const unsigned short*)x, flag);

  bias_k<<<128, 256, 0, stream>>>(rel_bias, bias_s, flag);
  conv_w_k<<<768, 256, 0, stream>>>(qkv_w, qkvWt, 256, 768, flag);
  conv3_k<<<768, 256, 0, stream>>>(proj_w, fc1_w, fc2_w, projWt, fc1Wt, fc2Wt,
                                   flag);

  bf16* h = reg1;  // LN1 out
  ln_k<<<M / 4, 256, 0, stream>>>(x, n1g, n1b, h, flag, 1);

  bf16* qkv = reg2;  // [M][768]
  gemm_bt_k<0><<<dim3(6, M / 128), 256, 0, stream>>>(
      h, qkvWt, qkv_b, nullptr, qkv, M, 768, 256, flag, 0, 0);

  bf16* o = reg1;  // overwrites h (dead)
  attn_k<<<2048 * 8 / 4, 256, 0, stream>>>(qkv, bias_s, o);

  bf16* x2 = reg2;  // overwrites qkv (dead)
  gemm_bt_k<2><<<dim3(2, M / 128), 256, 0, stream>>>(
      o, projWt, proj_b, x, x2, M, 256, 256, flag, 1, 0);

  bf16* mbuf = reg1;  // overwrites o (dead)
  ln_k<<<M / 4, 256, 0, stream>>>(x2, n2g, n2b, mbuf, flag, 0);

  bf16* m1 = reg2 + 33554432;  // after x2 (64 MiB in)
  gemm_bt_k<1><<<dim3(2, M / 128), 256, 0, stream>>>(
      mbuf, fc1Wt, fc1_b, nullptr, m1, M, 256, 256, flag, 0, 0);

  gemm_bt_k<2><<<dim3(2, M / 128), 256, 0, stream>>>(
      m1, fc2Wt, fc2_b, x2, d_out, M, 256, 256, flag, 0, 1);
}

// Round 8
// 718.767 us; speedup vs baseline: 1.1319x; 1.1319x over previous
//
#include <hip/hip_runtime.h>
#include <stdint.h>

typedef __bf16 bf16;
typedef __bf16 bf16x4v __attribute__((ext_vector_type(4)));
typedef __bf16 bf16x8 __attribute__((ext_vector_type(8)));
typedef float floatx4 __attribute__((ext_vector_type(4)));
typedef float float4v __attribute__((ext_vector_type(4)));

#define SCALE 0.17677669529663689f

// load input element i as float, honoring runtime dtype flag (1 = fp32, 0 = bf16)
__device__ __forceinline__ float ldin(const void* p, long i, int f32) {
  return f32 ? ((const float*)p)[i] : (float)(((const bf16*)p)[i]);
}

// async global->LDS DMA, 16B per lane. lds ptr must be wave-uniform;
// HW writes lds_base + lane*16.
__device__ __forceinline__ void async16(const bf16* g, bf16* l) {
  __builtin_amdgcn_global_load_lds(
      (const __attribute__((address_space(1))) void*)g,
      (__attribute__((address_space(3))) void*)l, 16, 0, 0);
}

// ---------------- dtype detector ----------------
__global__ void detect_k(const unsigned short* __restrict__ x, int* flag) {
  __shared__ int cnt;
  if (threadIdx.x == 0) cnt = 0;
  __syncthreads();
  int local = 0;
  for (int i = threadIdx.x; i < 4096; i += 256) {
    unsigned short w = x[i];
    int e = (w >> 7) & 0xFF;
    if (w != 0 && (e >= 0x9F || e <= 0x5F)) local++;
  }
  atomicAdd(&cnt, local);
  __syncthreads();
  if (threadIdx.x == 0) *flag = (cnt >= 64) ? 1 : 0;
}

// ---------------- weight convert+transpose: W[K][N] -> Wt[N][K] (bf16) ----------------
__global__ void conv_w_k(const void* __restrict__ W, bf16* __restrict__ Wt,
                         int K, int N, const int* __restrict__ flag) {
  int f32 = *flag;
  int idx = blockIdx.x * 256 + threadIdx.x;
  if (idx < K * N) {
    int k = idx / N, n = idx % N;
    Wt[n * K + k] = (bf16)ldin(W, idx, f32);
  }
}

// three 256x256 weight converts in one launch
__global__ void conv3_k(const void* __restrict__ W0, const void* __restrict__ W1,
                        const void* __restrict__ W2, bf16* __restrict__ T0,
                        bf16* __restrict__ T1, bf16* __restrict__ T2,
                        const int* __restrict__ flag) {
  int f32 = *flag;
  int which = blockIdx.x >> 8;
  int idx = (blockIdx.x & 255) * 256 + threadIdx.x;
  const void* W = which == 0 ? W0 : which == 1 ? W1 : W2;
  bf16* T = which == 0 ? T0 : which == 1 ? T1 : T2;
  int k = idx >> 8, n = idx & 255;
  T[n * 256 + k] = (bf16)ldin(W, idx, f32);
}

// ---------------- rel-bias precompute into MFMA C-order table ----------------
// bias_s[head][quad][l16][mi][ni][r]  (fp32, 32768 entries = 128 KB)
__global__ void bias_k(const void* __restrict__ rel, float* __restrict__ bias_s,
                       const int* __restrict__ flag) {
  int f = *flag;
  int idx = blockIdx.x * 256 + threadIdx.x;  // 0..32767
  int r = idx & 3, ni = (idx >> 2) & 3, mi = (idx >> 4) & 3;
  int l16 = (idx >> 6) & 15, quad = (idx >> 10) & 3, head = idx >> 12;
  int i = mi * 16 + quad * 4 + r, j = ni * 16 + l16;
  int dy = (i >> 3) - (j >> 3) + 7, dx = (i & 7) - (j & 7) + 7;
  bias_s[idx] = ldin(rel, (dy * 15 + dx) * 8 + head, f);
}

// ---------------- LayerNorm: rows of 256, 1 wave per row ----------------
__global__ __launch_bounds__(256) void ln_k(const void* __restrict__ x,
                                            const void* __restrict__ g,
                                            const void* __restrict__ b,
                                            bf16* __restrict__ y,
                                            const int* __restrict__ flag,
                                            int x_input) {
  int f = *flag;
  int f32x = x_input ? f : 0;
  int wave = threadIdx.x >> 6, lane = threadIdx.x & 63;
  long row = (long)blockIdx.x * 4 + wave;
  float v[4];
  if (f32x) {
    float4v u = ((const float4v*)x)[row * 64 + lane];
    for (int i = 0; i < 4; i++) v[i] = u[i];
  } else {
    bf16x4v u = ((const bf16x4v*)x)[row * 64 + lane];
    for (int i = 0; i < 4; i++) v[i] = (float)u[i];
  }
  float s = v[0] + v[1] + v[2] + v[3];
  for (int off = 32; off > 0; off >>= 1) s += __shfl_xor(s, off, 64);
  float mean = s * (1.f / 256.f);
  float q = 0.f;
  for (int i = 0; i < 4; i++) { float d = v[i] - mean; q += d * d; }
  for (int off = 32; off > 0; off >>= 1) q += __shfl_xor(q, off, 64);
  float rstd = rsqrtf(q * (1.f / 256.f) + 1e-5f);
  bf16x4v o;
  for (int i = 0; i < 4; i++) {
    float gv = ldin(g, lane * 4 + i, f);
    float bv = ldin(b, lane * 4 + i, f);
    o[i] = (bf16)((v[i] - mean) * rstd * gv + bv);
  }
  ((bf16x4v*)y)[row * 64 + lane] = o;
}

// ------------- GEMM C[M][N] = A[M][K] @ Bt[N][K]^T + bias (+epilogue) -------------
// grid = dim3(N/128, M/128), bijective XCD chunk swizzle.
// K-loop: TRIPLE-buffered stage (global_load_lds w=16) with counted vmcnt:
//   two tiles stay in flight across each barrier (vmcnt(8)) — each tile gets
//   ~2 K-step periods (~800cy) to land, matching the L3-hit latency of A
//   (FETCH shows A is L3-resident). Depth 2 (R6) only covered ~400cy -> +3us.
//   sched_barrier(0) fences per rule #18; asm idioms identical to verified R6.
// Source-side XOR swizzle on the global k-chunk + same XOR on fragment ds_read
// keeps LDS bank conflicts at 0 (verified R2).
// Epilogue stages C through LDS (CsF aliases the tile buffers) so stores are
// wide & line-coalesced; EPI==2 residual added in store phase, vectorized.
template <int EPI>
__global__ __launch_bounds__(256) void gemm_bt_k(
    const bf16* __restrict__ A, const bf16* __restrict__ Bt,
    const void* __restrict__ bias, const void* __restrict__ res,
    void* __restrict__ C, int M, int N, int K, const int* __restrict__ flag,
    int res_input, int out_input) {
  __shared__ __align__(16) char smem[49152];  // 3 x (8KB A + 8KB B)
  bf16* Sb = (bf16*)smem;
  float* CsF = (float*)smem;  // 32x132 fp32, live only after K-loop

  const int tid = threadIdx.x;
  const int ntiles = gridDim.x;  // N/128
  int bid = blockIdx.y * ntiles + blockIdx.x;
  const int nwg = ntiles * gridDim.y;
  if (!(nwg & 7)) bid = (bid & 7) * (nwg >> 3) + (bid >> 3);  // XCD chunking
  const long m0 = (long)(bid / ntiles) * 128;
  const int n0 = (bid % ntiles) * 128;
  const int wave = tid >> 6, lane = tid & 63;
  const int wm = wave & 1, wn = wave >> 1;
  const int quad = lane >> 4, l16 = lane & 15;

  floatx4 acc[4][4];
  for (int i = 0; i < 4; i++)
    for (int j = 0; j < 4; j++) acc[i][j] = (floatx4){0.f, 0.f, 0.f, 0.f};

  const int ldr = tid >> 2;
  // source-side swizzle: lds slot (row, c) receives global chunk c ^ ((row>>1)&3)
  const int ldc = (((tid & 3) ^ ((tid >> 3) & 3)) << 3);

  const bf16* gA0 = A + (m0 + ldr) * K + ldc;
  const bf16* gA1 = A + (m0 + 64 + ldr) * K + ldc;
  const bf16* gB0 = Bt + (long)(n0 + ldr) * K + ldc;
  const bf16* gB1 = Bt + (long)(n0 + 64 + ldr) * K + ldc;

  const int rswz = (l16 >> 1) & 3;  // read-side XOR (row = ..16.. + l16)
  const int NT = K >> 5;            // K-tiles (8 for K=256); NT >= 3 assumed

  // stage tile tt into buffer b (4 DMAs per wave, wave-uniform LDS bases)
#define STAGE(b, tt)                                   \
  do {                                                 \
    bf16* _base = Sb + (b) * 8192 + wave * 512;        \
    int _kt = (tt) << 5;                               \
    async16(gA0 + _kt, _base);                         \
    async16(gA1 + _kt, _base + 2048);                  \
    async16(gB0 + _kt, _base + 4096);                  \
    async16(gB1 + _kt, _base + 6144);                  \
  } while (0)

  STAGE(0, 0);
  STAGE(1, 1);
  STAGE(2, 2);  // 12 loads in flight

  int buf = 0;
  for (int t = 0; t < NT; ++t) {
    const int ahead = NT - 1 - t;  // tiles still in flight after this wait
    // tile t's 4 loads landed; up to 2 later tiles' 8 loads stay in flight
    if (ahead >= 2)
      asm volatile("s_waitcnt vmcnt(8)" ::: "memory");
    else if (ahead == 1)
      asm volatile("s_waitcnt vmcnt(4)" ::: "memory");
    else
      asm volatile("s_waitcnt vmcnt(0)" ::: "memory");
    __builtin_amdgcn_s_barrier();   // all waves' tile-t loads visible
    __builtin_amdgcn_sched_barrier(0);
    const bf16* As_t = Sb + buf * 8192;
    const bf16* Bs_t = As_t + 4096;
    bf16x8 af[4], bfr[4];
    for (int mi = 0; mi < 4; mi++)
      af[mi] = *(const bf16x8*)&As_t[(wm * 64 + mi * 16 + l16) * 32 +
                                     ((quad ^ rswz) << 3)];
    for (int ni = 0; ni < 4; ni++)
      bfr[ni] = *(const bf16x8*)&Bs_t[(wn * 64 + ni * 16 + l16) * 32 +
                                      ((quad ^ rswz) << 3)];
    asm volatile("s_waitcnt lgkmcnt(0)" ::: "memory");  // my reads in regs
    __builtin_amdgcn_sched_barrier(0);
    __builtin_amdgcn_s_barrier();   // all waves done reading buf -> WAR safe
    __builtin_amdgcn_sched_barrier(0);
    if (t + 3 < NT) STAGE(buf, t + 3);  // refill the buffer just consumed
    for (int mi = 0; mi < 4; mi++)
      for (int ni = 0; ni < 4; ni++)
        acc[mi][ni] = __builtin_amdgcn_mfma_f32_16x16x32_bf16(
            af[mi], bfr[ni], acc[mi][ni], 0, 0, 0);
    buf = (buf == 2) ? 0 : buf + 1;
  }
#undef STAGE

  const int f = *flag;
  const int rf32 = res_input ? f : 0;
  const int of32 = out_input ? f : 0;
  for (int mi = 0; mi < 4; mi++) {
    __syncthreads();  // CsF free (K-loop reads / prev store phase done)
    // ---- reg phase: bias / GELU, stage into LDS ----
    for (int ni = 0; ni < 4; ni++) {
      int col = n0 + wn * 64 + ni * 16 + l16;
      float bv = ldin(bias, col, f);
      for (int r = 0; r < 4; r++) {
        float v = acc[mi][ni][r] + bv;
        if (EPI == 1) v = v * 0.5f * (1.f + erff(v * 0.70710678118654752f));
        CsF[(wm * 16 + quad * 4 + r) * 132 + wn * 64 + ni * 16 + l16] = v;
      }
    }
    __syncthreads();
    // ---- store phase: each thread writes 16 contiguous cols of one row ----
    const int s = tid >> 3;   // 0..31 staged rows
    const int seg = tid & 7;  // 8 x 16-col segments
    const long grow = m0 + (s >> 4) * 64 + mi * 16 + (s & 15);
    const int gcol = n0 + seg * 16;
    const float4v* src = (const float4v*)&CsF[s * 132 + seg * 16];
    float4v v0 = src[0], v1 = src[1], v2 = src[2], v3 = src[3];
    if (EPI == 2) {  // residual add, vectorized & coalesced
      if (rf32) {
        const float4v* rp = (const float4v*)((const float*)res + grow * N + gcol);
        v0 += rp[0]; v1 += rp[1]; v2 += rp[2]; v3 += rp[3];
      } else {
        const bf16x8* rp = (const bf16x8*)((const bf16*)res + grow * N + gcol);
        bf16x8 r0 = rp[0], r1 = rp[1];
        for (int j = 0; j < 4; j++) {
          v0[j] += (float)r0[j];     v1[j] += (float)r0[4 + j];
          v2[j] += (float)r1[j];     v3[j] += (float)r1[4 + j];
        }
      }
    }
    if (of32) {
      float4v* dst = (float4v*)((float*)C + grow * N + gcol);
      dst[0] = v0; dst[1] = v1; dst[2] = v2; dst[3] = v3;
    } else {
      bf16x8 o0, o1;
      for (int j = 0; j < 4; j++) {
        o0[j] = (bf16)v0[j]; o0[4 + j] = (bf16)v1[j];
        o1[j] = (bf16)v2[j]; o1[4 + j] = (bf16)v3[j];
      }
      bf16x8* dst = (bf16x8*)((bf16*)C + grow * N + gcol);
      dst[0] = o0; dst[1] = o1;
    }
  }
}

// ---------------- MFMA windowed attention ----------------
// 1 wave = 1 (window, head); block = 4 heads of same window.
// qkv: [131072][768] bf16; o: [131072][256] bf16; bias_s: MFMA C-order fp32.
__global__ __launch_bounds__(256) void attn_k(const bf16* __restrict__ qkv,
                                              const float* __restrict__ bias_s,
                                              bf16* __restrict__ o) {
  __shared__ bf16 Pb[4][64 * 64];
  __shared__ bf16 Vb[4][32 * 64];
  const int tid = threadIdx.x;
  const int wave = tid >> 6, lane = tid & 63;
  const int quad = lane >> 4, l16 = lane & 15;
  const int gid = blockIdx.x * 4 + wave;
  const int head = gid & 7, win = gid >> 3;
  const int wx = win & 15, wy = (win >> 4) & 15, bb = win >> 8;

  bf16* P = Pb[wave];
  bf16* Vt = Vb[wave];

  // --- load Q,K fragments direct from global; V natural -> LDS transposed ---
  bf16x8 qf[4], kf[4];
  for (int mi = 0; mi < 4; mi++) {
    int t = mi * 16 + l16;
    int rr = (wy * 8 + (t >> 3) + 4) & 127;
    int cc = (wx * 8 + (t & 7) + 4) & 127;
    long base = ((long)(bb * 16384 + rr * 128 + cc)) * 768 + head * 32 + quad * 8;
    qf[mi] = *(const bf16x8*)(qkv + base);
    kf[mi] = *(const bf16x8*)(qkv + base + 256);
    bf16x8 vv = *(const bf16x8*)(qkv + base + 512);
    // Vt[d][t] stored at d*64 + (t ^ ((d>>3)<<4)); here d = quad*8+jj, d>>3 = quad
    int tcol = t ^ (quad << 4);
    for (int jj = 0; jj < 8; jj++) Vt[(quad * 8 + jj) * 64 + tcol] = vv[jj];
  }
  __syncthreads();

  // --- S = Q K^T (16 MFMAs, K=32 single step) ---
  floatx4 acc[4][4];
  for (int mi = 0; mi < 4; mi++)
    for (int ni = 0; ni < 4; ni++) {
      floatx4 z = (floatx4){0.f, 0.f, 0.f, 0.f};
      acc[mi][ni] = __builtin_amdgcn_mfma_f32_16x16x32_bf16(qf[mi], kf[ni], z, 0, 0, 0);
    }

  // --- scale + bias + row softmax (rows live in one quad -> shfl over l16) ---
  const float4v* bp =
      (const float4v*)(bias_s + (((head * 4 + quad) * 16 + l16) << 6));
  for (int mi = 0; mi < 4; mi++) {
    float mx[4] = {-1e30f, -1e30f, -1e30f, -1e30f};
    for (int ni = 0; ni < 4; ni++) {
      float4v bv = bp[mi * 4 + ni];
      for (int r = 0; r < 4; r++) {
        acc[mi][ni][r] = acc[mi][ni][r] * SCALE + bv[r];
        mx[r] = fmaxf(mx[r], acc[mi][ni][r]);
      }
    }
    for (int r = 0; r < 4; r++) {
      float m = mx[r];
      for (int off = 1; off < 16; off <<= 1) m = fmaxf(m, __shfl_xor(m, off, 64));
      mx[r] = m;
    }
    float sm[4] = {0.f, 0.f, 0.f, 0.f};
    for (int ni = 0; ni < 4; ni++)
      for (int r = 0; r < 4; r++) {
        float e = __expf(acc[mi][ni][r] - mx[r]);
        acc[mi][ni][r] = e;
        sm[r] += e;
      }
    for (int r = 0; r < 4; r++) {
      float s = sm[r];
      for (int off = 1; off < 16; off <<= 1) s += __shfl_xor(s, off, 64);
      sm[r] = 1.f / s;
    }
    // P[i][j] stored at i*64 + (j ^ ((i&7)<<3))
    for (int ni = 0; ni < 4; ni++)
      for (int r = 0; r < 4; r++) {
        int i = mi * 16 + quad * 4 + r;
        int j = ni * 16 + l16;
        P[i * 64 + (j ^ ((i & 7) << 3))] = (bf16)(acc[mi][ni][r] * sm[r]);
      }
  }
  __syncthreads();

  // --- O = P V (16 MFMAs over 2 K-steps) ---
  floatx4 oacc[4][2];
  for (int mi = 0; mi < 4; mi++)
    for (int nt = 0; nt < 2; nt++) oacc[mi][nt] = (floatx4){0.f, 0.f, 0.f, 0.f};
  for (int ks = 0; ks < 2; ks++) {
    bf16x8 vfr[2];
    for (int nt = 0; nt < 2; nt++) {
      int d = nt * 16 + l16;
      vfr[nt] =
          *(const bf16x8*)&Vt[d * 64 + ((ks * 32 + quad * 8) ^ ((d >> 3) << 4))];
    }
    for (int mi = 0; mi < 4; mi++) {
      int i = mi * 16 + l16;
      bf16x8 pf =
          *(const bf16x8*)&P[i * 64 + ((ks * 32 + quad * 8) ^ ((i & 7) << 3))];
      for (int nt = 0; nt < 2; nt++)
        oacc[mi][nt] = __builtin_amdgcn_mfma_f32_16x16x32_bf16(pf, vfr[nt],
                                                               oacc[mi][nt], 0, 0, 0);
    }
  }

  // --- stage O into Vt (wave-private, dead after PV; chunk-rotated to spread
  //     banks) then write 64B per token with 4x16B stores ---
  for (int mi = 0; mi < 4; mi++)
    for (int r = 0; r < 4; r++) {
      int t = mi * 16 + quad * 4 + r;
      int rot = (t >> 1) & 3;
      int c0 = l16, c1 = 16 + l16;
      Vt[t * 32 + ((((c0 >> 3) + rot) & 3) << 3) + (c0 & 7)] = (bf16)oacc[mi][0][r];
      Vt[t * 32 + ((((c1 >> 3) + rot) & 3) << 3) + (c1 & 7)] = (bf16)oacc[mi][1][r];
    }
  {
    int t = lane;
    int rot = (t >> 1) & 3;
    int rr = (wy * 8 + (t >> 3) + 4) & 127;
    int cc = (wx * 8 + (t & 7) + 4) & 127;
    long base = ((long)(bb * 16384 + rr * 128 + cc)) * 256 + head * 32;
    bf16x8* dst = (bf16x8*)(o + base);
    for (int k = 0; k < 4; k++)
      dst[k] = *(const bf16x8*)&Vt[t * 32 + (((k + rot) & 3) << 3)];
  }
}

extern "C" void kernel_launch(void* const* d_in, const int* in_sizes, int n_in,
                              void* d_out, int out_size, void* d_ws,
                              size_t ws_size, hipStream_t stream) {
  const void* x = d_in[0];
  const void* n1g = d_in[1];
  const void* n1b = d_in[2];
  const void* qkv_w = d_in[3];
  const void* qkv_b = d_in[4];
  const void* rel_bias = d_in[5];
  const void* proj_w = d_in[6];
  const void* proj_b = d_in[7];
  const void* n2g = d_in[8];
  const void* n2b = d_in[9];
  const void* fc1_w = d_in[10];
  const void* fc1_b = d_in[11];
  const void* fc2_w = d_in[12];
  const void* fc2_b = d_in[13];

  char* ws = (char*)d_ws;
  int* flag = (int*)ws;
  float* bias_s = (float*)(ws + 4096);        // 128 KB
  bf16* qkvWt = (bf16*)(ws + 262144);         // 768*256 bf16
  bf16* projWt = qkvWt + 768 * 256;
  bf16* fc1Wt = projWt + 256 * 256;
  bf16* fc2Wt = fc1Wt + 256 * 256;
  bf16* reg1 = (bf16*)(ws + (1 << 20));                  // 64 MiB region
  bf16* reg2 = (bf16*)(ws + (1 << 20) + 67108864);       // 192 MiB region

  const int M = 131072;  // 8 * 16384 tokens

  detect_k<<<1, 256, 0, stream>>>((const unsigned short*)x, flag);

  bias_k<<<128, 256, 0, stream>>>(rel_bias, bias_s, flag);
  conv_w_k<<<768, 256, 0, stream>>>(qkv_w, qkvWt, 256, 768, flag);
  conv3_k<<<768, 256, 0, stream>>>(proj_w, fc1_w, fc2_w, projWt, fc1Wt, fc2Wt,
                                   flag);

  bf16* h = reg1;  // LN1 out
  ln_k<<<M / 4, 256, 0, stream>>>(x, n1g, n1b, h, flag, 1);

  bf16* qkv = reg2;  // [M][768]
  gemm_bt_k<0><<<dim3(6, M / 128), 256, 0, stream>>>(
      h, qkvWt, qkv_b, nullptr, qkv, M, 768, 256, flag, 0, 0);

  bf16* o = reg1;  // overwrites h (dead)
  attn_k<<<2048 * 8 / 4, 256, 0, stream>>>(qkv, bias_s, o);

  bf16* x2 = reg2;  // overwrites qkv (dead)
  gemm_bt_k<2><<<dim3(2, M / 128), 256, 0, stream>>>(
      o, projWt, proj_b, x, x2, M, 256, 256, flag, 1, 0);

  bf16* mbuf = reg1;  // overwrites o (dead)
  ln_k<<<M / 4, 256, 0, stream>>>(x2, n2g, n2b, mbuf, flag, 0);

  bf16* m1 = reg2 + 33554432;  // after x2 (64 MiB in)
  gemm_bt_k<1><<<dim3(2, M / 128), 256, 0, stream>>>(
      mbuf, fc1Wt, fc1_b, nullptr, m1, M, 256, 256, flag, 0, 0);

  gemm_bt_k<2><<<dim3(2, M / 128), 256, 0, stream>>>(
      m1, fc2Wt, fc2_b, x2, d_out, M, 256, 256, flag, 0, 1);
}